// Round 13
// baseline (585.484 us; speedup 1.0000x reference)
//
#include <hip/hip_runtime.h>
#include <hip/hip_bf16.h>

typedef __attribute__((ext_vector_type(8))) short bf16x8;
typedef __attribute__((ext_vector_type(4))) float f32x4;

constexpr int ND = 128;   // node dim
constexpr int HD = 256;   // hidden dim
constexpr int ED = 64;    // edge dim
constexpr int ET = 32;    // edges per block tile (was 64: acc[4][4]=64 AGPR
                          // pinned occupancy at 4 waves/SIMD; ET=32 -> 32 AGPR
                          // + launch_bounds(256,5) -> guaranteed 5 waves/SIMD)
constexpr int MPn = 200;  // m pitch bf16
constexpr int HP  = 264;  // hid pitch bf16 (528B)
constexpr int MSGP = 132; // msg pitch f32 (528B)

// fast silu: v * rcp(1+exp(-v))
__device__ __forceinline__ float silu_f(float v) {
    float e = __expf(-v);
    return v * __builtin_amdgcn_rcpf(1.0f + e);
}
__device__ __forceinline__ __hip_bfloat16 f2b(float v) { return __float2bfloat16(v); }
__device__ __forceinline__ unsigned short f2bu(float v) {
    __hip_bfloat16 b = __float2bfloat16(v);
    return *(unsigned short*)&b;
}
__device__ __forceinline__ float bu2f(unsigned short u) {
    unsigned int t = ((unsigned int)u) << 16;
    return __uint_as_float(t);
}

// ---------- fused prep A: h->bf16 (8x vectorized) + dst histogram + weight swizzle ----------
__global__ __launch_bounds__(256) void prep_fused_a(
    const float* __restrict__ h, __hip_bfloat16* __restrict__ hb, int nh,
    const int* __restrict__ eidx, int* __restrict__ cnt, int E, int nbH,
    const float* __restrict__ Wn1, const float* __restrict__ Wc1,
    const float* __restrict__ Wn2, const float* __restrict__ We2,
    const float* __restrict__ bn1, const float* __restrict__ bc1,
    const float* __restrict__ be2,
    __hip_bfloat16* __restrict__ Wn1s, __hip_bfloat16* __restrict__ Wc1s,
    __hip_bfloat16* __restrict__ Wn2s,
    float* __restrict__ bn1p, float* __restrict__ bc1p)
{
    if ((int)blockIdx.x < nbH) {
        int j = blockIdx.x * 256 + threadIdx.x;
        int base = j * 8;
        if (base < nh) {                     // 8 h elems per thread, vectorized
            const float4* hp = (const float4*)(h + base);
            float4 v0 = hp[0], v1 = hp[1];
            uint4 o;
            o.x = (unsigned)f2bu(v0.x) | ((unsigned)f2bu(v0.y) << 16);
            o.y = (unsigned)f2bu(v0.z) | ((unsigned)f2bu(v0.w) << 16);
            o.z = (unsigned)f2bu(v1.x) | ((unsigned)f2bu(v1.y) << 16);
            o.w = (unsigned)f2bu(v1.z) | ((unsigned)f2bu(v1.w) << 16);
            ((uint4*)hb)[j] = o;
        }
        if (j < E) atomicAdd(&cnt[eidx[E + j]], 1);
        return;
    }
    int id = (blockIdx.x - nbH) * 256 + threadIdx.x;
    if (id < 163840) {                      // Wn1s / Wc1s: 10 ks * 16 nt * 64 * 8
        int e = id;
        const float* W = Wn1; __hip_bfloat16* out = Wn1s;
        if (id >= 81920) { e -= 81920; W = Wc1; out = Wc1s; }
        int j = e & 7, lane = (e >> 3) & 63, nt = (e >> 9) & 15, ks = e >> 13;
        int k = ks * 32 + (lane >> 4) * 8 + j;
        int n = nt * 16 + (lane & 15);
        float v;
        if (k < 2 * ND) v = W[k * HD + n];
        else {
            int t = k - 2 * ND; v = 0.f;
            for (int u = 0; u < ED; ++u) v += We2[t * ED + u] * W[(2 * ND + u) * HD + n];
        }
        out[e] = f2b(v);
    } else if (id < 196608) {               // Wn2s: k permuted to swizzled hid cols
        int e = id - 163840;
        int j = e & 7, lane = (e >> 3) & 63, nt = (e >> 9) & 7, ks = e >> 12;
        int kk = ks * 32 + (lane >> 4) * 8 + j;
        int k = (kk >> 6) * 64 + (kk & 3) * 16 + ((kk >> 2) & 15);
        int n = nt * 16 + (lane & 15);
        Wn2s[e] = f2b(Wn2[k * ND + n]);
    } else if (id < 197120) {               // folded biases
        int n = id - 196608;
        if (n < HD) {
            float v = bn1[n];
            for (int t = 0; t < ED; ++t) v += be2[t] * Wn1[(2 * ND + t) * HD + n];
            bn1p[n] = v;
        } else {
            int m = n - HD;
            float v = bc1[m];
            for (int t = 0; t < ED; ++t) v += be2[t] * Wc1[(2 * ND + t) * HD + m];
            bc1p[m] = v;
        }
    }
}

// ---------- counting sort scans ----------
__global__ __launch_bounds__(256) void s_scan1(const int* __restrict__ cnt,
                                               int* __restrict__ bsum, int N) {
    __shared__ int sh[256];
    int i = blockIdx.x * 256 + threadIdx.x;
    sh[threadIdx.x] = (i < N) ? cnt[i] : 0;
    __syncthreads();
    for (int s = 128; s > 0; s >>= 1) {
        if (threadIdx.x < s) sh[threadIdx.x] += sh[threadIdx.x + s];
        __syncthreads();
    }
    if (threadIdx.x == 0) bsum[blockIdx.x] = sh[0];
}

__global__ __launch_bounds__(256) void s_scan2(int* __restrict__ bsum, int nb) {
    __shared__ int sh[256];
    int t = threadIdx.x;
    int orig = (t < nb) ? bsum[t] : 0;
    sh[t] = orig;
    __syncthreads();
    for (int off = 1; off < 256; off <<= 1) {
        int u = (t >= off) ? sh[t - off] : 0;
        __syncthreads();
        sh[t] += u;
        __syncthreads();
    }
    if (t < nb) bsum[t] = sh[t] - orig;   // exclusive
}

__global__ __launch_bounds__(256) void s_scan3(const int* __restrict__ cnt,
                                               const int* __restrict__ bsum,
                                               int* __restrict__ head, int N) {
    __shared__ int sh[256];
    int t = threadIdx.x, i = blockIdx.x * 256 + t;
    int v = (i < N) ? cnt[i] : 0;
    sh[t] = v;
    __syncthreads();
    for (int off = 1; off < 256; off <<= 1) {
        int u = (t >= off) ? sh[t - off] : 0;
        __syncthreads();
        sh[t] += u;
        __syncthreads();
    }
    if (i < N) head[i] = bsum[blockIdx.x] + sh[t] - v;  // exclusive prefix
}

// ---------- fused prep B: edge scatter + Q GEMM (independent of ET) ----------
__global__ __launch_bounds__(256) void prep_fused_b(
    const int* __restrict__ eidx, const float* __restrict__ dist,
    int* __restrict__ head, int4* __restrict__ sedge, int E, int nbE,
    const __hip_bfloat16* __restrict__ hb,
    const __hip_bfloat16* __restrict__ Wn1s,
    const __hip_bfloat16* __restrict__ Wc1s,
    unsigned short* __restrict__ Q, int N)
{
    __shared__ __align__(16) __hip_bfloat16 a_sh[64 * 136];
    if ((int)blockIdx.x < nbE) {
        int e = blockIdx.x * 256 + threadIdx.x;
        if (e < E) {
            int d = eidx[E + e];
            int pos = atomicAdd(&head[d], 1);
            int4 v; v.x = eidx[e]; v.y = d; v.z = __float_as_int(dist[e]); v.w = 0;
            sedge[pos] = v;
        }
        return;
    }
    // ---- prep_q part ----
    const int tid = threadIdx.x;
    const int lane = tid & 63, wv = tid >> 6;
    const int q = lane >> 4, lc = lane & 15;
    const int row0 = (blockIdx.x - nbE) * 64;

    for (int i = tid; i < 64 * 16; i += 256) {
        int r = i >> 4, piece = i & 15;
        int node = min(row0 + r, N - 1);
        uint4 v = ((const uint4*)(hb + (size_t)node * ND))[piece];
        *((uint4*)((char*)a_sh + r * 272 + piece * 16)) = v;
    }
    __syncthreads();

    for (int pass = 0; pass < 2; ++pass) {
        const __hip_bfloat16* Ws = pass ? Wc1s : Wn1s;
        f32x4 acc[4][4];
        #pragma unroll
        for (int rt = 0; rt < 4; ++rt)
            #pragma unroll
            for (int nti = 0; nti < 4; ++nti) acc[rt][nti] = (f32x4){0.f, 0.f, 0.f, 0.f};

        for (int ks = 0; ks < 4; ++ks) {
            bf16x8 a[4];
            #pragma unroll
            for (int rt = 0; rt < 4; ++rt)
                a[rt] = *(const bf16x8*)&a_sh[(rt * 16 + lc) * 136 + ks * 32 + q * 8];
            #pragma unroll
            for (int nti = 0; nti < 4; ++nti) {
                bf16x8 b = *(const bf16x8*)&Ws[(((ks + 4) * 16 + wv * 4 + nti) * 64 + lane) * 8];
                #pragma unroll
                for (int rt = 0; rt < 4; ++rt)
                    acc[rt][nti] = __builtin_amdgcn_mfma_f32_16x16x32_bf16(a[rt], b, acc[rt][nti], 0, 0, 0);
            }
        }
        #pragma unroll
        for (int rt = 0; rt < 4; ++rt)
            #pragma unroll
            for (int r = 0; r < 4; ++r) {
                int node = row0 + rt * 16 + q * 4 + r;
                if (node < N) {
                    ushort4 us;
                    us.x = f2bu(acc[rt][0][r]); us.y = f2bu(acc[rt][1][r]);
                    us.z = f2bu(acc[rt][2][r]); us.w = f2bu(acc[rt][3][r]);
                    ((ushort4*)Q)[((size_t)node * 2 + pass) * 64 + wv * 16 + lc] = us;
                }
            }
    }
}

// ---------- main fused edge kernel ----------
// ET=32 retile of the proven 378us structure: acc[2][4] = 32 AGPR (was 64).
// __launch_bounds__(256, 5) caps the allocator at 102 regs/wave (demand ~88)
// -> GUARANTEED 5 waves/SIMD (20 waves/CU, 62.5%) vs the old 4/41.8%. The
// kernel is issue/latency-bound (VALU 57 + MFMA 25 = 82% combined issue,
// HBM 6%): more resident waves fill the residual stall slots. All other
// proven choices kept: JIT-Q (Qb base), GEMM1 ks-loops ROLLED (#pragma
// unroll 1; unrolling spills), msg natural col order, We1/be1 hoisted,
// coord flush hoisted, hin prefetch.
__global__ __launch_bounds__(256, 5) void egnn_main(
    const __hip_bfloat16* __restrict__ hb,
    const float* __restrict__ hin,
    const float* __restrict__ x,
    const int4* __restrict__ sedge,
    const __hip_bfloat16* __restrict__ Wn1s,
    const __hip_bfloat16* __restrict__ Wc1s,
    const __hip_bfloat16* __restrict__ Wn2s,
    const unsigned short* __restrict__ Q,
    const float* __restrict__ bn1p, const float* __restrict__ bc1p,
    const float* __restrict__ bn2,  const float* __restrict__ Wc2,
    const float* __restrict__ We1,  const float* __restrict__ be1,
    float* __restrict__ outp,
    float* __restrict__ spillF, float* __restrict__ spillL,
    float* __restrict__ cspF,   float* __restrict__ cspL,
    int E, int nhOff)
{
    __shared__ __align__(16) unsigned char smem[ET * HP * 2];   // m_sh / hid / msg
    __shared__ float dir_sh[ET * 3];
    __shared__ float coordw_part[4][ET];   // per-wave partials, no atomics
    __shared__ float dist_sh[ET];
    __shared__ int   sidx[ET], didx[ET];
    __shared__ int   seg_start[ET + 1];
    __shared__ int   nseg_sh;

    __hip_bfloat16* m_sh = (__hip_bfloat16*)smem;

    const int tid  = threadIdx.x;
    const int lane = tid & 63;
    const int wv   = tid >> 6;
    const int q    = lane >> 4;
    const int lc   = lane & 15;
    const int e0   = blockIdx.x * ET;
    const int nv   = min(ET, E - e0);

    // per-thread Q base (ushort4 units): Q4[node*128 + pass*64 + (wv*16+lc)]
    const ushort4* Qb = ((const ushort4*)Q) + (wv * 16 + lc);

    if (tid < ET) {
        int e = min(e0 + tid, E - 1);
        int4 v = sedge[e];
        int s = v.x, d = v.y;
        sidx[tid] = s; didx[tid] = d;
        dist_sh[tid] = __int_as_float(v.z);
        #pragma unroll
        for (int c = 0; c < 3; ++c) dir_sh[tid * 3 + c] = x[s * 3 + c] - x[d * 3 + c];
    }
    __syncthreads();

    // segment table (wave 0 only; lanes >= ET produce no flags)
    if (wv == 0) {
        bool valid = lane < nv;
        bool flag = valid && (lane == 0 || didx[lane] != didx[lane - 1]);
        unsigned long long mask = __ballot(flag);
        if (flag) {
            int s = __popcll(mask & ((1ull << lane) - 1ull));
            seg_start[s] = lane;
        }
        if (lane == 0) {
            int ns = __popcll(mask);
            nseg_sh = ns;
            seg_start[ns] = nv;
        }
    }

    // gather h[src] -> m[:,0:128]
    for (int i = tid; i < ET * 16; i += 256) {
        int er = i >> 4, piece = i & 15;
        uint4 v = ((const uint4*)(hb + (size_t)sidx[er] * ND))[piece];
        *((uint4*)((char*)m_sh + er * (MPn * 2) + piece * 16)) = v;
    }
    // se = silu(dist*We1+be1) -> m[:,128:192]; 2 cols/thread, ushort2 stores
    {
        int jp = tid & 31;
        float w0 = We1[2 * jp], w1 = We1[2 * jp + 1];
        float b0 = be1[2 * jp], b1 = be1[2 * jp + 1];
        int erb = tid >> 5;
        #pragma unroll
        for (int k = 0; k < 4; ++k) {         // 8 erb * 4 k = 32 rows
            int er = erb + 8 * k;
            float d = dist_sh[er];
            ushort2 st;
            st.x = f2bu(silu_f(fmaf(d, w0, b0)));
            st.y = f2bu(silu_f(fmaf(d, w1, b1)));
            *(ushort2*)&m_sh[er * MPn + ND + 2 * jp] = st;
        }
    }
    __syncthreads();

    // ---- GEMM1 pass A: coord hidden (acc[2][4] = 32 regs) ----
    {
        f32x4 acc[2][4];
        #pragma unroll
        for (int nti = 0; nti < 4; ++nti) {
            float b = bc1p[(wv * 4 + nti) * 16 + lc];
            #pragma unroll
            for (int rt = 0; rt < 2; ++rt) acc[rt][nti] = (f32x4){b, b, b, b};
        }
        #pragma unroll 1
        for (int ks = 0; ks < 6; ++ks) {
            int bk = (ks < 4) ? ks : ks + 4;
            bf16x8 a[2];
            #pragma unroll
            for (int rt = 0; rt < 2; ++rt)
                a[rt] = *(const bf16x8*)&m_sh[(rt * 16 + lc) * MPn + ks * 32 + q * 8];
            #pragma unroll
            for (int nti = 0; nti < 4; ++nti) {
                bf16x8 b = *(const bf16x8*)&Wc1s[((bk * 16 + wv * 4 + nti) * 64 + lane) * 8];
                #pragma unroll
                for (int rt = 0; rt < 2; ++rt)
                    acc[rt][nti] = __builtin_amdgcn_mfma_f32_16x16x32_bf16(a[rt], b, acc[rt][nti], 0, 0, 0);
            }
        }
        float wcv[4];
        #pragma unroll
        for (int nti = 0; nti < 4; ++nti) wcv[nti] = Wc2[(wv * 4 + nti) * 16 + lc];
        #pragma unroll
        for (int rt = 0; rt < 2; ++rt) {
            #pragma unroll
            for (int r = 0; r < 4; ++r) {
                int node = didx[rt * 16 + q * 4 + r];
                ushort4 us = Qb[(size_t)node * 128 + 64];
                float pv = 0.f;
                pv += silu_f(acc[rt][0][r] + bu2f(us.x)) * wcv[0];
                pv += silu_f(acc[rt][1][r] + bu2f(us.y)) * wcv[1];
                pv += silu_f(acc[rt][2][r] + bu2f(us.z)) * wcv[2];
                pv += silu_f(acc[rt][3][r] + bu2f(us.w)) * wcv[3];
                pv += __shfl_xor(pv, 1); pv += __shfl_xor(pv, 2);
                pv += __shfl_xor(pv, 4); pv += __shfl_xor(pv, 8);
                if (lc == 0) coordw_part[wv][rt * 16 + q * 4 + r] = pv;
            }
        }
    }

    // ---- GEMM1 pass B: node hidden ----
    f32x4 accn[2][4];
    #pragma unroll
    for (int nti = 0; nti < 4; ++nti) {
        float b = bn1p[(wv * 4 + nti) * 16 + lc];
        #pragma unroll
        for (int rt = 0; rt < 2; ++rt) accn[rt][nti] = (f32x4){b, b, b, b};
    }
    #pragma unroll 1
    for (int ks = 0; ks < 6; ++ks) {
        int bk = (ks < 4) ? ks : ks + 4;
        bf16x8 a[2];
        #pragma unroll
        for (int rt = 0; rt < 2; ++rt)
            a[rt] = *(const bf16x8*)&m_sh[(rt * 16 + lc) * MPn + ks * 32 + q * 8];
        #pragma unroll
        for (int nti = 0; nti < 4; ++nti) {
            bf16x8 b = *(const bf16x8*)&Wn1s[((bk * 16 + wv * 4 + nti) * 64 + lane) * 8];
            #pragma unroll
            for (int rt = 0; rt < 2; ++rt)
                accn[rt][nti] = __builtin_amdgcn_mfma_f32_16x16x32_bf16(a[rt], b, accn[rt][nti], 0, 0, 0);
        }
    }
    __syncthreads();   // bar2: all m_sh reads done; coordw_part complete

    // coord flush HOISTED: stores overlap hid-write/GEMM2/msg
    {
        int nseg = nseg_sh;
        for (int u = tid; u < nseg * 3; u += 256) {
            int s = u / 3, c = u - s * 3;
            int r0 = seg_start[s], r1 = seg_start[s + 1];
            float run = 0.f;
            for (int r = r0; r < r1; ++r) {
                float w = coordw_part[0][r] + coordw_part[1][r]
                        + coordw_part[2][r] + coordw_part[3][r];
                run += w * dir_sh[r * 3 + c];
            }
            if (s == 0)             cspF[blockIdx.x * 3 + c] = run;
            else if (s == nseg - 1) cspL[blockIdx.x * 3 + c] = run;
            else {
                int n = didx[r0];
                outp[(size_t)nhOff + n * 3 + c] = x[n * 3 + c] + run;
            }
        }
    }
    // prefetch hin for this thread's first interior h-flush unit (u == tid)
    f32x4 hv0 = (f32x4){0.f, 0.f, 0.f, 0.f};
    bool pre0 = false;
    {
        int nseg = nseg_sh;
        int s = tid >> 5;
        if (tid < nseg * 32 && s > 0 && s < nseg - 1) {
            int n = didx[seg_start[s]];
            hv0 = *(const f32x4*)&hin[(size_t)n * ND + (tid & 31) * 4];
            pre0 = true;
        }
    }

    // hid = silu(accn + Q[node,pass0]), col-swizzled (c' = wv*64 + lc*4 + nti)
    __hip_bfloat16* hid = (__hip_bfloat16*)smem;
    #pragma unroll
    for (int rt = 0; rt < 2; ++rt) {
        #pragma unroll
        for (int r = 0; r < 4; ++r) {
            int row = rt * 16 + q * 4 + r;
            int node = didx[row];
            ushort4 us = Qb[(size_t)node * 128];
            ushort4 hv;
            hv.x = f2bu(silu_f(accn[rt][0][r] + bu2f(us.x)));
            hv.y = f2bu(silu_f(accn[rt][1][r] + bu2f(us.y)));
            hv.z = f2bu(silu_f(accn[rt][2][r] + bu2f(us.z)));
            hv.w = f2bu(silu_f(accn[rt][3][r] + bu2f(us.w)));
            *(ushort4*)&hid[row * HP + wv * 64 + lc * 4] = hv;
        }
    }
    __syncthreads();

    // ---- GEMM2: msg = hid @ Wn2 + bn2 (acc2[2][2] = 16 regs) ----
    f32x4 acc2[2][2];
    #pragma unroll
    for (int nti = 0; nti < 2; ++nti) {
        float b = bn2[(wv * 2 + nti) * 16 + lc];
        #pragma unroll
        for (int rt = 0; rt < 2; ++rt) acc2[rt][nti] = (f32x4){b, b, b, b};
    }
    #pragma unroll 2
    for (int ks = 0; ks < 8; ++ks) {
        bf16x8 a[2];
        #pragma unroll
        for (int rt = 0; rt < 2; ++rt)
            a[rt] = *(const bf16x8*)&hid[(rt * 16 + lc) * HP + ks * 32 + q * 8];
        #pragma unroll
        for (int nti = 0; nti < 2; ++nti) {
            bf16x8 b = *(const bf16x8*)&Wn2s[((ks * 8 + wv * 2 + nti) * 64 + lane) * 8];
            #pragma unroll
            for (int rt = 0; rt < 2; ++rt)
                acc2[rt][nti] = __builtin_amdgcn_mfma_f32_16x16x32_bf16(a[rt], b, acc2[rt][nti], 0, 0, 0);
        }
    }
    __syncthreads();   // waves done reading hid

    // msg in NATURAL column order: col = (wv*2+nti)*16 + lc
    float* msg = (float*)smem;
    #pragma unroll
    for (int rt = 0; rt < 2; ++rt)
        #pragma unroll
        for (int r = 0; r < 4; ++r) {
            int row = rt * 16 + q * 4 + r;
            msg[row * MSGP + (wv * 2 + 0) * 16 + lc] = acc2[rt][0][r];
            msg[row * MSGP + (wv * 2 + 1) * 16 + lc] = acc2[rt][1][r];
        }
    __syncthreads();

    // ---- segmented h flush: NO atomics; aligned f32x4 msg reads ----
    {
        int nseg = nseg_sh;
        for (int u = tid; u < nseg * 32; u += 256) {
            int s  = u >> 5;
            int c4 = (u & 31) * 4;
            int r0 = seg_start[s], r1 = seg_start[s + 1];
            f32x4 run = (f32x4){0.f, 0.f, 0.f, 0.f};
            for (int r = r0; r < r1; ++r)
                run += *(const f32x4*)&msg[r * MSGP + c4];
            if (s == 0) {
                *(f32x4*)&spillF[(size_t)blockIdx.x * ND + c4] = run;
            } else if (s == nseg - 1) {
                *(f32x4*)&spillL[(size_t)blockIdx.x * ND + c4] = run;
            } else {
                int n = didx[r0];
                f32x4 hv = (u == tid && pre0) ? hv0
                         : *(const f32x4*)&hin[(size_t)n * ND + c4];
                *(f32x4*)&outp[(size_t)n * ND + c4] = run + hv;
            }
        }
    }
}

// ---------- finalize: boundary + deg-0 nodes only, f32x4-vectorized ----------
// ET=32: block index math uses >>5 / <<5
__global__ __launch_bounds__(256) void egnn_finalize(
    const float* __restrict__ h, const float* __restrict__ x,
    const float* __restrict__ spillF, const float* __restrict__ spillL,
    const float* __restrict__ cspF,   const float* __restrict__ cspL,
    const int* __restrict__ headEnd,  const int* __restrict__ cnt,
    float* __restrict__ out, int n_nodes, int E)
{
    int i = blockIdx.x * 256 + threadIdx.x;
    int nh4 = n_nodes * (ND / 4);          // 4-col groups
    int total = nh4 + n_nodes * 3;
    if (i < nh4) {
        int n  = i >> 5;                   // ND/4 = 32 groups per node
        int c4 = (i & 31) * 4;
        int deg = cnt[n];
        if (deg > 0) {
            int e_end   = headEnd[n];      // after scatter, head[n] = end offset
            int e_start = e_end - deg;
            int b0 = e_start >> 5, b1 = (e_end - 1) >> 5;   // ET = 32
            bool interior = (e_start > (b0 << 5)) && (e_end < min((b0 + 1) << 5, E));
            if (interior) return;          // egnn_main wrote final value
            f32x4 v = *(const f32x4*)&h[(size_t)n * ND + c4];
            for (int b = b0; b <= b1; ++b) {
                if ((b << 5) >= e_start)                v += *(const f32x4*)&spillF[(size_t)b * ND + c4];
                else if (min((b + 1) << 5, E) <= e_end) v += *(const f32x4*)&spillL[(size_t)b * ND + c4];
            }
            *(f32x4*)&out[(size_t)n * ND + c4] = v;
        } else {
            *(f32x4*)&out[(size_t)n * ND + c4] = *(const f32x4*)&h[(size_t)n * ND + c4];
        }
    } else if (i < total) {
        int k = i - nh4;
        int n = k / 3, c = k - n * 3;
        int deg = cnt[n];
        int nh = n_nodes * ND;
        if (deg > 0) {
            int e_end   = headEnd[n];
            int e_start = e_end - deg;
            int b0 = e_start >> 5, b1 = (e_end - 1) >> 5;
            bool interior = (e_start > (b0 << 5)) && (e_end < min((b0 + 1) << 5, E));
            if (interior) return;
            float v = x[k];
            for (int b = b0; b <= b1; ++b) {
                if ((b << 5) >= e_start)                v += cspF[b * 3 + c];
                else if (min((b + 1) << 5, E) <= e_end) v += cspL[b * 3 + c];
            }
            out[nh + k] = v;
        } else {
            out[nh + k] = x[k];
        }
    }
}

extern "C" void kernel_launch(void* const* d_in, const int* in_sizes, int n_in,
                              void* d_out, int out_size, void* d_ws, size_t ws_size,
                              hipStream_t stream)
{
    const float* h    = (const float*)d_in[0];
    const float* x    = (const float*)d_in[1];
    const int*   eidx = (const int*)d_in[2];
    const float* dist = (const float*)d_in[3];
    const float* Wn1  = (const float*)d_in[4];
    const float* bn1  = (const float*)d_in[5];
    const float* Wn2  = (const float*)d_in[6];
    const float* bn2  = (const float*)d_in[7];
    const float* Wc1  = (const float*)d_in[8];
    const float* bc1  = (const float*)d_in[9];
    const float* Wc2  = (const float*)d_in[10];
    const float* We1  = (const float*)d_in[11];
    const float* be1  = (const float*)d_in[12];
    const float* We2  = (const float*)d_in[13];
    const float* be2  = (const float*)d_in[14];

    const int E = in_sizes[3];
    const int N = in_sizes[0] / ND;
    const int NB = (E + ET - 1) / ET;      // 25000 at ET=32

    // workspace layout (16B-aligned segments) — total ~103.8 MB (== round-0 proven)
    float* bn1p  = (float*)d_ws;                           // HD
    float* bc1p  = bn1p + HD;                              // HD
    __hip_bfloat16* hb   = (__hip_bfloat16*)(bc1p + HD);   // N*ND bf16
    __hip_bfloat16* Wn1s = hb + (size_t)N * ND;            // 81920
    __hip_bfloat16* Wc1s = Wn1s + 81920;                   // 81920
    __hip_bfloat16* Wn2s = Wc1s + 81920;                   // 32768
    int*   cnt   = (int*)(Wn2s + 32768);                   // N
    int*   bsum  = cnt + N;                                // 256
    int*   head  = bsum + 256;                             // N
    int4*  sedge = (int4*)(head + N);                      // E int4
    unsigned short* Q = (unsigned short*)(sedge + E);      // N*512
    float* spillF = (float*)(Q + (size_t)N * 512);         // NB*ND
    float* spillL = spillF + (size_t)NB * ND;              // NB*ND
    float* cspF   = spillL + (size_t)NB * ND;              // NB*3
    float* cspL   = cspF + (size_t)NB * 3;                 // NB*3

    hipMemsetAsync(cnt, 0, (size_t)N * sizeof(int), stream);

    const int nbN = (N + 255) / 256;
    const int nbE = (E + 255) / 256;
    const int nh  = N * ND;
    const int nhv = nh / 8;                                // 8 elems/thread
    const int nbH = ((nhv > E ? nhv : E) + 255) / 256;
    const int nbQ = (N + 63) / 64;

    prep_fused_a<<<nbH + 770, 256, 0, stream>>>(
        h, hb, nh, eidx, cnt, E, nbH,
        Wn1, Wc1, Wn2, We2, bn1, bc1, be2, Wn1s, Wc1s, Wn2s, bn1p, bc1p);
    s_scan1<<<nbN, 256, 0, stream>>>(cnt, bsum, N);
    s_scan2<<<1,   256, 0, stream>>>(bsum, nbN);
    s_scan3<<<nbN, 256, 0, stream>>>(cnt, bsum, head, N);
    prep_fused_b<<<nbE + nbQ, 256, 0, stream>>>(
        eidx, dist, head, sedge, E, nbE, hb, Wn1s, Wc1s, Q, N);

    egnn_main<<<NB, 256, 0, stream>>>(
        hb, h, x, sedge, Wn1s, Wc1s, Wn2s, Q, bn1p, bc1p, bn2, Wc2,
        We1, be1, (float*)d_out, spillF, spillL, cspF, cspL, E, nh);

    int totalF = N * (ND / 4) + N * 3;
    egnn_finalize<<<(totalF + 255) / 256, 256, 0, stream>>>(
        h, x, spillF, spillL, cspF, cspL, head, cnt,
        (float*)d_out, N, E);
}

// Round 14
// 571.860 us; speedup vs baseline: 1.0238x; 1.0238x over previous
//
#include <hip/hip_runtime.h>
#include <hip/hip_bf16.h>

typedef __attribute__((ext_vector_type(8))) short bf16x8;
typedef __attribute__((ext_vector_type(4))) float f32x4;

constexpr int ND = 128;   // node dim
constexpr int HD = 256;   // hidden dim
constexpr int ED = 64;    // edge dim
constexpr int ET = 64;    // edges per block tile (ET=32/6-wave variant measured
                          // WORSE: 391 vs 378us at 75% occ -- issue-bound, not
                          // latency-bound; keep the proven ET=64 tile)
constexpr int MPn = 200;  // m pitch bf16
constexpr int HP  = 264;  // hid pitch bf16 (528B)
constexpr int MSGP = 132; // msg pitch f32 (528B)

// fast silu: v * rcp(1+exp(-v))
__device__ __forceinline__ float silu_f(float v) {
    float e = __expf(-v);
    return v * __builtin_amdgcn_rcpf(1.0f + e);
}
__device__ __forceinline__ __hip_bfloat16 f2b(float v) { return __float2bfloat16(v); }
__device__ __forceinline__ unsigned short f2bu(float v) {
    __hip_bfloat16 b = __float2bfloat16(v);
    return *(unsigned short*)&b;
}
__device__ __forceinline__ float bu2f(unsigned short u) {
    unsigned int t = ((unsigned int)u) << 16;
    return __uint_as_float(t);
}

// ---------- fused prep A: h->bf16 (8x vectorized) + dst histogram + weight swizzle ----------
__global__ __launch_bounds__(256) void prep_fused_a(
    const float* __restrict__ h, __hip_bfloat16* __restrict__ hb, int nh,
    const int* __restrict__ eidx, int* __restrict__ cnt, int E, int nbH,
    const float* __restrict__ Wn1, const float* __restrict__ Wc1,
    const float* __restrict__ Wn2, const float* __restrict__ We2,
    const float* __restrict__ bn1, const float* __restrict__ bc1,
    const float* __restrict__ be2,
    __hip_bfloat16* __restrict__ Wn1s, __hip_bfloat16* __restrict__ Wc1s,
    __hip_bfloat16* __restrict__ Wn2s,
    float* __restrict__ bn1p, float* __restrict__ bc1p)
{
    if ((int)blockIdx.x < nbH) {
        int j = blockIdx.x * 256 + threadIdx.x;
        int base = j * 8;
        if (base < nh) {                     // 8 h elems per thread, vectorized
            const float4* hp = (const float4*)(h + base);
            float4 v0 = hp[0], v1 = hp[1];
            uint4 o;
            o.x = (unsigned)f2bu(v0.x) | ((unsigned)f2bu(v0.y) << 16);
            o.y = (unsigned)f2bu(v0.z) | ((unsigned)f2bu(v0.w) << 16);
            o.z = (unsigned)f2bu(v1.x) | ((unsigned)f2bu(v1.y) << 16);
            o.w = (unsigned)f2bu(v1.z) | ((unsigned)f2bu(v1.w) << 16);
            ((uint4*)hb)[j] = o;
        }
        if (j < E) atomicAdd(&cnt[eidx[E + j]], 1);
        return;
    }
    int id = (blockIdx.x - nbH) * 256 + threadIdx.x;
    if (id < 163840) {                      // Wn1s / Wc1s: 10 ks * 16 nt * 64 * 8
        int e = id;
        const float* W = Wn1; __hip_bfloat16* out = Wn1s;
        if (id >= 81920) { e -= 81920; W = Wc1; out = Wc1s; }
        int j = e & 7, lane = (e >> 3) & 63, nt = (e >> 9) & 15, ks = e >> 13;
        int k = ks * 32 + (lane >> 4) * 8 + j;
        int n = nt * 16 + (lane & 15);
        float v;
        if (k < 2 * ND) v = W[k * HD + n];
        else {
            int t = k - 2 * ND; v = 0.f;
            for (int u = 0; u < ED; ++u) v += We2[t * ED + u] * W[(2 * ND + u) * HD + n];
        }
        out[e] = f2b(v);
    } else if (id < 196608) {               // Wn2s: k permuted to swizzled hid cols
        int e = id - 163840;
        int j = e & 7, lane = (e >> 3) & 63, nt = (e >> 9) & 7, ks = e >> 12;
        int kk = ks * 32 + (lane >> 4) * 8 + j;
        int k = (kk >> 6) * 64 + (kk & 3) * 16 + ((kk >> 2) & 15);
        int n = nt * 16 + (lane & 15);
        Wn2s[e] = f2b(Wn2[k * ND + n]);
    } else if (id < 197120) {               // folded biases
        int n = id - 196608;
        if (n < HD) {
            float v = bn1[n];
            for (int t = 0; t < ED; ++t) v += be2[t] * Wn1[(2 * ND + t) * HD + n];
            bn1p[n] = v;
        } else {
            int m = n - HD;
            float v = bc1[m];
            for (int t = 0; t < ED; ++t) v += be2[t] * Wc1[(2 * ND + t) * HD + m];
            bc1p[m] = v;
        }
    }
}

// ---------- counting sort scans ----------
__global__ __launch_bounds__(256) void s_scan1(const int* __restrict__ cnt,
                                               int* __restrict__ bsum, int N) {
    __shared__ int sh[256];
    int i = blockIdx.x * 256 + threadIdx.x;
    sh[threadIdx.x] = (i < N) ? cnt[i] : 0;
    __syncthreads();
    for (int s = 128; s > 0; s >>= 1) {
        if (threadIdx.x < s) sh[threadIdx.x] += sh[threadIdx.x + s];
        __syncthreads();
    }
    if (threadIdx.x == 0) bsum[blockIdx.x] = sh[0];
}

__global__ __launch_bounds__(256) void s_scan2(int* __restrict__ bsum, int nb) {
    __shared__ int sh[256];
    int t = threadIdx.x;
    int orig = (t < nb) ? bsum[t] : 0;
    sh[t] = orig;
    __syncthreads();
    for (int off = 1; off < 256; off <<= 1) {
        int u = (t >= off) ? sh[t - off] : 0;
        __syncthreads();
        sh[t] += u;
        __syncthreads();
    }
    if (t < nb) bsum[t] = sh[t] - orig;   // exclusive
}

__global__ __launch_bounds__(256) void s_scan3(const int* __restrict__ cnt,
                                               const int* __restrict__ bsum,
                                               int* __restrict__ head, int N) {
    __shared__ int sh[256];
    int t = threadIdx.x, i = blockIdx.x * 256 + t;
    int v = (i < N) ? cnt[i] : 0;
    sh[t] = v;
    __syncthreads();
    for (int off = 1; off < 256; off <<= 1) {
        int u = (t >= off) ? sh[t - off] : 0;
        __syncthreads();
        sh[t] += u;
        __syncthreads();
    }
    if (i < N) head[i] = bsum[blockIdx.x] + sh[t] - v;  // exclusive prefix
}

// ---------- fused prep B: edge scatter + Q GEMM ----------
__global__ __launch_bounds__(256) void prep_fused_b(
    const int* __restrict__ eidx, const float* __restrict__ dist,
    int* __restrict__ head, int4* __restrict__ sedge, int E, int nbE,
    const __hip_bfloat16* __restrict__ hb,
    const __hip_bfloat16* __restrict__ Wn1s,
    const __hip_bfloat16* __restrict__ Wc1s,
    unsigned short* __restrict__ Q, int N)
{
    __shared__ __align__(16) __hip_bfloat16 a_sh[64 * 136];
    if ((int)blockIdx.x < nbE) {
        int e = blockIdx.x * 256 + threadIdx.x;
        if (e < E) {
            int d = eidx[E + e];
            int pos = atomicAdd(&head[d], 1);
            int4 v; v.x = eidx[e]; v.y = d; v.z = __float_as_int(dist[e]); v.w = 0;
            sedge[pos] = v;
        }
        return;
    }
    // ---- prep_q part ----
    const int tid = threadIdx.x;
    const int lane = tid & 63, wv = tid >> 6;
    const int q = lane >> 4, lc = lane & 15;
    const int row0 = (blockIdx.x - nbE) * 64;

    for (int i = tid; i < 64 * 16; i += 256) {
        int r = i >> 4, piece = i & 15;
        int node = min(row0 + r, N - 1);
        uint4 v = ((const uint4*)(hb + (size_t)node * ND))[piece];
        *((uint4*)((char*)a_sh + r * 272 + piece * 16)) = v;
    }
    __syncthreads();

    for (int pass = 0; pass < 2; ++pass) {
        const __hip_bfloat16* Ws = pass ? Wc1s : Wn1s;
        f32x4 acc[4][4];
        #pragma unroll
        for (int rt = 0; rt < 4; ++rt)
            #pragma unroll
            for (int nti = 0; nti < 4; ++nti) acc[rt][nti] = (f32x4){0.f, 0.f, 0.f, 0.f};

        for (int ks = 0; ks < 4; ++ks) {
            bf16x8 a[4];
            #pragma unroll
            for (int rt = 0; rt < 4; ++rt)
                a[rt] = *(const bf16x8*)&a_sh[(rt * 16 + lc) * 136 + ks * 32 + q * 8];
            #pragma unroll
            for (int nti = 0; nti < 4; ++nti) {
                bf16x8 b = *(const bf16x8*)&Ws[(((ks + 4) * 16 + wv * 4 + nti) * 64 + lane) * 8];
                #pragma unroll
                for (int rt = 0; rt < 4; ++rt)
                    acc[rt][nti] = __builtin_amdgcn_mfma_f32_16x16x32_bf16(a[rt], b, acc[rt][nti], 0, 0, 0);
            }
        }
        #pragma unroll
        for (int rt = 0; rt < 4; ++rt)
            #pragma unroll
            for (int r = 0; r < 4; ++r) {
                int node = row0 + rt * 16 + q * 4 + r;
                if (node < N) {
                    ushort4 us;
                    us.x = f2bu(acc[rt][0][r]); us.y = f2bu(acc[rt][1][r]);
                    us.z = f2bu(acc[rt][2][r]); us.w = f2bu(acc[rt][3][r]);
                    ((ushort4*)Q)[((size_t)node * 2 + pass) * 64 + wv * 16 + lc] = us;
                }
            }
    }
}

// ---------- main fused edge kernel ----------
// FINAL proven structure (378us): JIT-Q (Qb base), acc[4][4], (256,4), GEMM1
// ks-loops ROLLED (#pragma unroll 1 -- unrolled trip-6 hoists 24 global
// B-frag loads and spills ~14 regs/thread; fix was 490->393us), msg natural
// col order, We1/be1 hoisted, coord flush hoisted after bar2, hin prefetch.
// Issue-bound floor: VALU 57 + MFMA 25 = 82% combined issue; occupancy
// experiments both directions (3 waves: 523us, 6 waves@ET=32: 391us) worse
// than this 4-wave/ET=64 point.
__global__ __launch_bounds__(256, 4) void egnn_main(
    const __hip_bfloat16* __restrict__ hb,
    const float* __restrict__ hin,
    const float* __restrict__ x,
    const int4* __restrict__ sedge,
    const __hip_bfloat16* __restrict__ Wn1s,
    const __hip_bfloat16* __restrict__ Wc1s,
    const __hip_bfloat16* __restrict__ Wn2s,
    const unsigned short* __restrict__ Q,
    const float* __restrict__ bn1p, const float* __restrict__ bc1p,
    const float* __restrict__ bn2,  const float* __restrict__ Wc2,
    const float* __restrict__ We1,  const float* __restrict__ be1,
    float* __restrict__ outp,
    float* __restrict__ spillF, float* __restrict__ spillL,
    float* __restrict__ cspF,   float* __restrict__ cspL,
    int E, int nhOff)
{
    __shared__ __align__(16) unsigned char smem[ET * HP * 2];
    __shared__ float dir_sh[ET * 3];
    __shared__ float coordw_part[4][ET];   // per-wave partials, no atomics
    __shared__ float dist_sh[ET];
    __shared__ int   sidx[ET], didx[ET];
    __shared__ int   seg_start[ET + 1];
    __shared__ int   nseg_sh;

    __hip_bfloat16* m_sh = (__hip_bfloat16*)smem;

    const int tid  = threadIdx.x;
    const int lane = tid & 63;
    const int wv   = tid >> 6;
    const int q    = lane >> 4;
    const int lc   = lane & 15;
    const int e0   = blockIdx.x * ET;
    const int nv   = min(ET, E - e0);

    // per-thread Q base (ushort4 units): Q4[node*128 + pass*64 + (wv*16+lc)]
    const ushort4* Qb = ((const ushort4*)Q) + (wv * 16 + lc);

    if (tid < ET) {
        int e = min(e0 + tid, E - 1);
        int4 v = sedge[e];
        int s = v.x, d = v.y;
        sidx[tid] = s; didx[tid] = d;
        dist_sh[tid] = __int_as_float(v.z);
        #pragma unroll
        for (int c = 0; c < 3; ++c) dir_sh[tid * 3 + c] = x[s * 3 + c] - x[d * 3 + c];
    }
    __syncthreads();

    // segment table (wave 0 only)
    if (wv == 0) {
        bool valid = lane < nv;
        bool flag = valid && (lane == 0 || didx[lane] != didx[lane - 1]);
        unsigned long long mask = __ballot(flag);
        if (flag) {
            int s = __popcll(mask & ((1ull << lane) - 1ull));
            seg_start[s] = lane;
        }
        if (lane == 0) {
            int ns = __popcll(mask);
            nseg_sh = ns;
            seg_start[ns] = nv;
        }
    }

    // gather h[src] -> m[:,0:128]
    for (int i = tid; i < ET * 16; i += 256) {
        int er = i >> 4, piece = i & 15;
        uint4 v = ((const uint4*)(hb + (size_t)sidx[er] * ND))[piece];
        *((uint4*)((char*)m_sh + er * (MPn * 2) + piece * 16)) = v;
    }
    // se = silu(dist*We1+be1) -> m[:,128:192]; 2 cols/thread, ushort2 stores
    {
        int jp = tid & 31;
        float w0 = We1[2 * jp], w1 = We1[2 * jp + 1];
        float b0 = be1[2 * jp], b1 = be1[2 * jp + 1];
        int erb = tid >> 5;
        #pragma unroll
        for (int k = 0; k < 8; ++k) {
            int er = erb + 8 * k;
            float d = dist_sh[er];
            ushort2 st;
            st.x = f2bu(silu_f(fmaf(d, w0, b0)));
            st.y = f2bu(silu_f(fmaf(d, w1, b1)));
            *(ushort2*)&m_sh[er * MPn + ND + 2 * jp] = st;
        }
    }
    __syncthreads();

    // ---- GEMM1 pass A: coord hidden ----
    {
        f32x4 acc[4][4];
        #pragma unroll
        for (int nti = 0; nti < 4; ++nti) {
            float b = bc1p[(wv * 4 + nti) * 16 + lc];
            #pragma unroll
            for (int rt = 0; rt < 4; ++rt) acc[rt][nti] = (f32x4){b, b, b, b};
        }
        #pragma unroll 1
        for (int ks = 0; ks < 6; ++ks) {
            int bk = (ks < 4) ? ks : ks + 4;
            bf16x8 a[4];
            #pragma unroll
            for (int rt = 0; rt < 4; ++rt)
                a[rt] = *(const bf16x8*)&m_sh[(rt * 16 + lc) * MPn + ks * 32 + q * 8];
            #pragma unroll
            for (int nti = 0; nti < 4; ++nti) {
                bf16x8 b = *(const bf16x8*)&Wc1s[((bk * 16 + wv * 4 + nti) * 64 + lane) * 8];
                #pragma unroll
                for (int rt = 0; rt < 4; ++rt)
                    acc[rt][nti] = __builtin_amdgcn_mfma_f32_16x16x32_bf16(a[rt], b, acc[rt][nti], 0, 0, 0);
            }
        }
        float wcv[4];
        #pragma unroll
        for (int nti = 0; nti < 4; ++nti) wcv[nti] = Wc2[(wv * 4 + nti) * 16 + lc];
        #pragma unroll
        for (int rt = 0; rt < 4; ++rt) {
            #pragma unroll
            for (int r = 0; r < 4; ++r) {
                int node = didx[rt * 16 + q * 4 + r];
                ushort4 us = Qb[(size_t)node * 128 + 64];
                float pv = 0.f;
                pv += silu_f(acc[rt][0][r] + bu2f(us.x)) * wcv[0];
                pv += silu_f(acc[rt][1][r] + bu2f(us.y)) * wcv[1];
                pv += silu_f(acc[rt][2][r] + bu2f(us.z)) * wcv[2];
                pv += silu_f(acc[rt][3][r] + bu2f(us.w)) * wcv[3];
                pv += __shfl_xor(pv, 1); pv += __shfl_xor(pv, 2);
                pv += __shfl_xor(pv, 4); pv += __shfl_xor(pv, 8);
                if (lc == 0) coordw_part[wv][rt * 16 + q * 4 + r] = pv;
            }
        }
    }

    // ---- GEMM1 pass B: node hidden ----
    f32x4 accn[4][4];
    #pragma unroll
    for (int nti = 0; nti < 4; ++nti) {
        float b = bn1p[(wv * 4 + nti) * 16 + lc];
        #pragma unroll
        for (int rt = 0; rt < 4; ++rt) accn[rt][nti] = (f32x4){b, b, b, b};
    }
    #pragma unroll 1
    for (int ks = 0; ks < 6; ++ks) {
        int bk = (ks < 4) ? ks : ks + 4;
        bf16x8 a[4];
        #pragma unroll
        for (int rt = 0; rt < 4; ++rt)
            a[rt] = *(const bf16x8*)&m_sh[(rt * 16 + lc) * MPn + ks * 32 + q * 8];
        #pragma unroll
        for (int nti = 0; nti < 4; ++nti) {
            bf16x8 b = *(const bf16x8*)&Wn1s[((bk * 16 + wv * 4 + nti) * 64 + lane) * 8];
            #pragma unroll
            for (int rt = 0; rt < 4; ++rt)
                accn[rt][nti] = __builtin_amdgcn_mfma_f32_16x16x32_bf16(a[rt], b, accn[rt][nti], 0, 0, 0);
        }
    }
    __syncthreads();   // bar2: all m_sh reads done; coordw_part complete

    // coord flush HOISTED: stores overlap hid-write/GEMM2/msg
    {
        int nseg = nseg_sh;
        for (int u = tid; u < nseg * 3; u += 256) {
            int s = u / 3, c = u - s * 3;
            int r0 = seg_start[s], r1 = seg_start[s + 1];
            float run = 0.f;
            for (int r = r0; r < r1; ++r) {
                float w = coordw_part[0][r] + coordw_part[1][r]
                        + coordw_part[2][r] + coordw_part[3][r];
                run += w * dir_sh[r * 3 + c];
            }
            if (s == 0)             cspF[blockIdx.x * 3 + c] = run;
            else if (s == nseg - 1) cspL[blockIdx.x * 3 + c] = run;
            else {
                int n = didx[r0];
                outp[(size_t)nhOff + n * 3 + c] = x[n * 3 + c] + run;
            }
        }
    }
    // prefetch hin for this thread's first interior h-flush unit (u == tid)
    f32x4 hv0 = (f32x4){0.f, 0.f, 0.f, 0.f};
    bool pre0 = false;
    {
        int nseg = nseg_sh;
        int s = tid >> 5;
        if (tid < nseg * 32 && s > 0 && s < nseg - 1) {
            int n = didx[seg_start[s]];
            hv0 = *(const f32x4*)&hin[(size_t)n * ND + (tid & 31) * 4];
            pre0 = true;
        }
    }

    // hid = silu(accn + Q[node,pass0]), col-swizzled (c' = wv*64 + lc*4 + nti)
    __hip_bfloat16* hid = (__hip_bfloat16*)smem;
    #pragma unroll
    for (int rt = 0; rt < 4; ++rt) {
        #pragma unroll
        for (int r = 0; r < 4; ++r) {
            int row = rt * 16 + q * 4 + r;
            int node = didx[row];
            ushort4 us = Qb[(size_t)node * 128];
            ushort4 hv;
            hv.x = f2bu(silu_f(accn[rt][0][r] + bu2f(us.x)));
            hv.y = f2bu(silu_f(accn[rt][1][r] + bu2f(us.y)));
            hv.z = f2bu(silu_f(accn[rt][2][r] + bu2f(us.z)));
            hv.w = f2bu(silu_f(accn[rt][3][r] + bu2f(us.w)));
            *(ushort4*)&hid[row * HP + wv * 64 + lc * 4] = hv;
        }
    }
    __syncthreads();

    // ---- GEMM2: msg = hid @ Wn2 + bn2 ----
    f32x4 acc2[4][2];
    #pragma unroll
    for (int nti = 0; nti < 2; ++nti) {
        float b = bn2[(wv * 2 + nti) * 16 + lc];
        #pragma unroll
        for (int rt = 0; rt < 4; ++rt) acc2[rt][nti] = (f32x4){b, b, b, b};
    }
    #pragma unroll 2
    for (int ks = 0; ks < 8; ++ks) {
        bf16x8 a[4];
        #pragma unroll
        for (int rt = 0; rt < 4; ++rt)
            a[rt] = *(const bf16x8*)&hid[(rt * 16 + lc) * HP + ks * 32 + q * 8];
        #pragma unroll
        for (int nti = 0; nti < 2; ++nti) {
            bf16x8 b = *(const bf16x8*)&Wn2s[((ks * 8 + wv * 2 + nti) * 64 + lane) * 8];
            #pragma unroll
            for (int rt = 0; rt < 4; ++rt)
                acc2[rt][nti] = __builtin_amdgcn_mfma_f32_16x16x32_bf16(a[rt], b, acc2[rt][nti], 0, 0, 0);
        }
    }
    __syncthreads();   // waves done reading hid

    // msg in NATURAL column order: col = (wv*2+nti)*16 + lc
    float* msg = (float*)smem;
    #pragma unroll
    for (int rt = 0; rt < 4; ++rt)
        #pragma unroll
        for (int r = 0; r < 4; ++r) {
            int row = rt * 16 + q * 4 + r;
            msg[row * MSGP + (wv * 2 + 0) * 16 + lc] = acc2[rt][0][r];
            msg[row * MSGP + (wv * 2 + 1) * 16 + lc] = acc2[rt][1][r];
        }
    __syncthreads();

    // ---- segmented h flush: NO atomics; aligned f32x4 msg reads ----
    {
        int nseg = nseg_sh;
        for (int u = tid; u < nseg * 32; u += 256) {
            int s  = u >> 5;
            int c4 = (u & 31) * 4;
            int r0 = seg_start[s], r1 = seg_start[s + 1];
            f32x4 run = (f32x4){0.f, 0.f, 0.f, 0.f};
            for (int r = r0; r < r1; ++r)
                run += *(const f32x4*)&msg[r * MSGP + c4];
            if (s == 0) {
                *(f32x4*)&spillF[(size_t)blockIdx.x * ND + c4] = run;
            } else if (s == nseg - 1) {
                *(f32x4*)&spillL[(size_t)blockIdx.x * ND + c4] = run;
            } else {
                int n = didx[r0];
                f32x4 hv = (u == tid && pre0) ? hv0
                         : *(const f32x4*)&hin[(size_t)n * ND + c4];
                *(f32x4*)&outp[(size_t)n * ND + c4] = run + hv;
            }
        }
    }
}

// ---------- finalize: boundary + deg-0 nodes only, f32x4-vectorized ----------
__global__ __launch_bounds__(256) void egnn_finalize(
    const float* __restrict__ h, const float* __restrict__ x,
    const float* __restrict__ spillF, const float* __restrict__ spillL,
    const float* __restrict__ cspF,   const float* __restrict__ cspL,
    const int* __restrict__ headEnd,  const int* __restrict__ cnt,
    float* __restrict__ out, int n_nodes, int E)
{
    int i = blockIdx.x * 256 + threadIdx.x;
    int nh4 = n_nodes * (ND / 4);          // 4-col groups
    int total = nh4 + n_nodes * 3;
    if (i < nh4) {
        int n  = i >> 5;                   // ND/4 = 32 groups per node
        int c4 = (i & 31) * 4;
        int deg = cnt[n];
        if (deg > 0) {
            int e_end   = headEnd[n];      // after scatter, head[n] = end offset
            int e_start = e_end - deg;
            int b0 = e_start >> 6, b1 = (e_end - 1) >> 6;   // ET = 64
            bool interior = (e_start > (b0 << 6)) && (e_end < min((b0 + 1) << 6, E));
            if (interior) return;          // egnn_main wrote final value
            f32x4 v = *(const f32x4*)&h[(size_t)n * ND + c4];
            for (int b = b0; b <= b1; ++b) {
                if ((b << 6) >= e_start)                v += *(const f32x4*)&spillF[(size_t)b * ND + c4];
                else if (min((b + 1) << 6, E) <= e_end) v += *(const f32x4*)&spillL[(size_t)b * ND + c4];
            }
            *(f32x4*)&out[(size_t)n * ND + c4] = v;
        } else {
            *(f32x4*)&out[(size_t)n * ND + c4] = *(const f32x4*)&h[(size_t)n * ND + c4];
        }
    } else if (i < total) {
        int k = i - nh4;
        int n = k / 3, c = k - n * 3;
        int deg = cnt[n];
        int nh = n_nodes * ND;
        if (deg > 0) {
            int e_end   = headEnd[n];
            int e_start = e_end - deg;
            int b0 = e_start >> 6, b1 = (e_end - 1) >> 6;
            bool interior = (e_start > (b0 << 6)) && (e_end < min((b0 + 1) << 6, E));
            if (interior) return;
            float v = x[k];
            for (int b = b0; b <= b1; ++b) {
                if ((b << 6) >= e_start)                v += cspF[b * 3 + c];
                else if (min((b + 1) << 6, E) <= e_end) v += cspL[b * 3 + c];
            }
            out[nh + k] = v;
        } else {
            out[nh + k] = x[k];
        }
    }
}

extern "C" void kernel_launch(void* const* d_in, const int* in_sizes, int n_in,
                              void* d_out, int out_size, void* d_ws, size_t ws_size,
                              hipStream_t stream)
{
    const float* h    = (const float*)d_in[0];
    const float* x    = (const float*)d_in[1];
    const int*   eidx = (const int*)d_in[2];
    const float* dist = (const float*)d_in[3];
    const float* Wn1  = (const float*)d_in[4];
    const float* bn1  = (const float*)d_in[5];
    const float* Wn2  = (const float*)d_in[6];
    const float* bn2  = (const float*)d_in[7];
    const float* Wc1  = (const float*)d_in[8];
    const float* bc1  = (const float*)d_in[9];
    const float* Wc2  = (const float*)d_in[10];
    const float* We1  = (const float*)d_in[11];
    const float* be1  = (const float*)d_in[12];
    const float* We2  = (const float*)d_in[13];
    const float* be2  = (const float*)d_in[14];

    const int E = in_sizes[3];
    const int N = in_sizes[0] / ND;
    const int NB = (E + ET - 1) / ET;

    // workspace layout (16B-aligned segments) — total ~90.7 MB
    float* bn1p  = (float*)d_ws;                           // HD
    float* bc1p  = bn1p + HD;                              // HD
    __hip_bfloat16* hb   = (__hip_bfloat16*)(bc1p + HD);   // N*ND bf16
    __hip_bfloat16* Wn1s = hb + (size_t)N * ND;            // 81920
    __hip_bfloat16* Wc1s = Wn1s + 81920;                   // 81920
    __hip_bfloat16* Wn2s = Wc1s + 81920;                   // 32768
    int*   cnt   = (int*)(Wn2s + 32768);                   // N
    int*   bsum  = cnt + N;                                // 256
    int*   head  = bsum + 256;                             // N
    int4*  sedge = (int4*)(head + N);                      // E int4
    unsigned short* Q = (unsigned short*)(sedge + E);      // N*512
    float* spillF = (float*)(Q + (size_t)N * 512);         // NB*ND
    float* spillL = spillF + (size_t)NB * ND;              // NB*ND
    float* cspF   = spillL + (size_t)NB * ND;              // NB*3
    float* cspL   = cspF + (size_t)NB * 3;                 // NB*3

    hipMemsetAsync(cnt, 0, (size_t)N * sizeof(int), stream);

    const int nbN = (N + 255) / 256;
    const int nbE = (E + 255) / 256;
    const int nh  = N * ND;
    const int nhv = nh / 8;                                // 8 elems/thread
    const int nbH = ((nhv > E ? nhv : E) + 255) / 256;
    const int nbQ = (N + 63) / 64;

    prep_fused_a<<<nbH + 770, 256, 0, stream>>>(
        h, hb, nh, eidx, cnt, E, nbH,
        Wn1, Wc1, Wn2, We2, bn1, bc1, be2, Wn1s, Wc1s, Wn2s, bn1p, bc1p);
    s_scan1<<<nbN, 256, 0, stream>>>(cnt, bsum, N);
    s_scan2<<<1,   256, 0, stream>>>(bsum, nbN);
    s_scan3<<<nbN, 256, 0, stream>>>(cnt, bsum, head, N);
    prep_fused_b<<<nbE + nbQ, 256, 0, stream>>>(
        eidx, dist, head, sedge, E, nbE, hb, Wn1s, Wc1s, Q, N);

    egnn_main<<<NB, 256, 0, stream>>>(
        hb, h, x, sedge, Wn1s, Wc1s, Wn2s, Q, bn1p, bc1p, bn2, Wc2,
        We1, be1, (float*)d_out, spillF, spillL, cspF, cspL, E, nh);

    int totalF = N * (ND / 4) + N * 3;
    egnn_finalize<<<(totalF + 255) / 256, 256, 0, stream>>>(
        h, x, spillF, spillL, cspF, cspL, head, cnt,
        (float*)d_out, N, E);
}